// Round 4
// baseline (2197.175 us; speedup 1.0000x reference)
//
#include <hip/hip_runtime.h>
#include <cstdint>

#define K_OFF 27
#define NDOWN 40000
#define NUP   160000
#define CDOWN 128
#define CSKIP 64
#define CCAT  192
#define COUT  96
#define TM    64
#define MT_D  5
#define B_BINS (K_OFF * NUP)      // 4,320,000 bins = total entries for conv

typedef __bf16 bf16x8 __attribute__((ext_vector_type(8)));
typedef float f32x4 __attribute__((ext_vector_type(4)));

__device__ __forceinline__ unsigned short f2b(float f) {
    unsigned int u = __float_as_uint(f);
    u += 0x7FFFu + ((u >> 16) & 1u);           // round-to-nearest-even
    return (unsigned short)(u >> 16);
}
__device__ __forceinline__ unsigned int pk2(float a, float b) {
    return (unsigned)f2b(a) | ((unsigned)f2b(b) << 16);
}
__device__ __forceinline__ float b2f(unsigned int lo16) {
    return __uint_as_float(lo16 << 16);
}

__device__ __forceinline__ void gll16(const void* gsrc, void* ldst) {
    auto g = reinterpret_cast<const __attribute__((address_space(1))) unsigned int*>(
        reinterpret_cast<uintptr_t>(gsrc));
    auto l = reinterpret_cast<__attribute__((address_space(3))) unsigned int*>(
        reinterpret_cast<uintptr_t>(ldst));
    __builtin_amdgcn_global_load_lds(g, l, 16, 0, 0);
}

// ---------------- precompute passes ----------------
__global__ void pack_down_kernel(const float* __restrict__ down,
                                 unsigned short* __restrict__ dbf) {
    int i = blockIdx.x * 256 + threadIdx.x;
    if (i >= NDOWN * CDOWN / 8) return;
    const float4* s = (const float4*)down + (long)i * 2;
    float4 v0 = s[0], v1 = s[1];
    uint4 o;
    o.x = pk2(v0.x, v0.y); o.y = pk2(v0.z, v0.w);
    o.z = pk2(v1.x, v1.y); o.w = pk2(v1.z, v1.w);
    ((uint4*)dbf)[i] = o;
}

__global__ void pack_w_kernel(const float* __restrict__ Wd, const float* __restrict__ Wc,
                              unsigned short* __restrict__ WdT, unsigned short* __restrict__ WcT) {
    int i = blockIdx.x * 256 + threadIdx.x;
    if (i < K_OFF * CDOWN * CDOWN) {
        int k = i / (CDOWN * CDOWN), rem = i % (CDOWN * CDOWN);
        int n = rem >> 7, c = rem & 127;
        WdT[i] = f2b(Wd[((long)k * CDOWN + c) * CDOWN + n]);
    }
    if (i < K_OFF * COUT * CCAT) {
        int k = i / (COUT * CCAT), rem = i % (COUT * CCAT);
        int n = rem / CCAT, c = rem % CCAT;
        WcT[i] = f2b(Wc[((long)k * CCAT + c) * COUT + n]);
    }
}

__global__ void pack_cat_kernel(const float* __restrict__ up, const float* __restrict__ skip,
                                unsigned short* __restrict__ cat) {
    const int t = threadIdx.x;
    const int j = blockIdx.x * 8 + t / 24;
    const int s = t % 24;
    const int e0 = s * 8;
    float4 v0, v1;
    if (e0 < CDOWN) {
        const float4* src = (const float4*)(up + (long)j * CDOWN + e0);
        v0 = src[0]; v1 = src[1];
        v0.x = fmaxf(v0.x, 0.f); v0.y = fmaxf(v0.y, 0.f);
        v0.z = fmaxf(v0.z, 0.f); v0.w = fmaxf(v0.w, 0.f);
        v1.x = fmaxf(v1.x, 0.f); v1.y = fmaxf(v1.y, 0.f);
        v1.z = fmaxf(v1.z, 0.f); v1.w = fmaxf(v1.w, 0.f);
    } else {
        const float4* src = (const float4*)(skip + (long)j * CSKIP + (e0 - CDOWN));
        v0 = src[0]; v1 = src[1];
    }
    uint4 o;
    o.x = pk2(v0.x, v0.y); o.y = pk2(v0.z, v0.w);
    o.z = pk2(v1.x, v1.y); o.w = pk2(v1.z, v1.w);
    ((uint4*)(cat + (long)j * CCAT))[s] = o;
}

// ---------------- deconv (scatter form, verified round 2) ----------------
__global__ __launch_bounds__(256, 2)
void deconv_fast(const unsigned short* __restrict__ dbf,
                 const unsigned short* __restrict__ WdT,
                 const int* __restrict__ in_idx,
                 const int* __restrict__ out_idx,
                 float* __restrict__ up) {
    __shared__ __align__(1024) unsigned short sA[TM * CDOWN];

    const int segs = (NDOWN / TM) / MT_D;
    const int bk = blockIdx.x / segs;
    const int tile0 = (blockIdx.x % segs) * MT_D;
    const int t = threadIdx.x;
    const int wave = t >> 6, lane = t & 63;
    const int col = lane & 15, quad = lane >> 4;
    const int wm = wave & 1, wn = wave >> 1;

    int srow[4], soff[4];
#pragma unroll
    for (int i = 0; i < 4; i++) {
        int c = wave * 256 + i * 64 + lane;
        int r = c >> 4, cc = c & 15;
        srow[i] = r;
        soff[i] = (cc ^ (r & 7)) * 16;
    }

    bf16x8 b[4][4];
    {
        const unsigned short* wb = WdT + (long)bk * CDOWN * CDOWN;
#pragma unroll
        for (int kk = 0; kk < 4; kk++)
#pragma unroll
            for (int nt = 0; nt < 4; nt++)
                b[kk][nt] = *(const bf16x8*)&wb[(wn * 64 + nt * 16 + col) * CDOWN + kk * 32 + quad * 8];
    }

    const long kBase = (long)bk * NDOWN;
    const char* sAc = (const char*)sA;

    for (int tt = 0; tt < MT_D; ++tt) {
        const int rowbase = (tile0 + tt) * TM;
#pragma unroll
        for (int i = 0; i < 4; i++) {
            const int j = in_idx[kBase + rowbase + srow[i]];
            gll16((const char*)dbf + (long)j * (CDOWN * 2) + soff[i],
                  (char*)sA + (wave * 4 + i) * 1024);
        }
        __syncthreads();

        f32x4 acc[2][4];
#pragma unroll
        for (int mi = 0; mi < 2; mi++)
#pragma unroll
            for (int nt = 0; nt < 4; nt++) acc[mi][nt] = (f32x4){0.f, 0.f, 0.f, 0.f};

#pragma unroll
        for (int kk = 0; kk < 4; kk++) {
            const int ch = kk * 4 + quad;
#pragma unroll
            for (int mi = 0; mi < 2; mi++) {
                const int row = wm * 32 + mi * 16 + col;
                bf16x8 a = *(const bf16x8*)(sAc + row * 256 + ((ch ^ (row & 7)) * 16));
#pragma unroll
                for (int nt = 0; nt < 4; nt++)
                    acc[mi][nt] = __builtin_amdgcn_mfma_f32_16x16x32_bf16(a, b[kk][nt], acc[mi][nt], 0, 0, 0);
            }
        }
        __syncthreads();

#pragma unroll
        for (int mi = 0; mi < 2; mi++)
#pragma unroll
            for (int r = 0; r < 4; r++) {
                const int lrow = wm * 32 + mi * 16 + quad * 4 + r;
                const long ob = (long)out_idx[kBase + rowbase + lrow] * CDOWN;
#pragma unroll
                for (int nt = 0; nt < 4; nt++)
                    atomicAdd(&up[ob + wn * 64 + nt * 16 + col], acc[mi][nt][r]);
            }
    }
}

// ---------------- inverse-CSR build (counting sort by k*NUP + out_idx) ----------------
__global__ void hist_kernel(const int* __restrict__ cv_out, unsigned int* __restrict__ hist) {
    const int i = blockIdx.x * 256 + threadIdx.x;     // grid.x = NUP/256 exactly
    const int k = blockIdx.y;
    const int j = cv_out[(long)k * NUP + i];
    atomicAdd(&hist[(long)k * NUP + j], 1u);
}

// block-wise exclusive scan: out = exclusive scan of in per 1024-block; aux[blk] = block total
__global__ void scan_blocks(const unsigned int* __restrict__ in, unsigned int* __restrict__ out,
                            unsigned int* __restrict__ aux, int n) {
    __shared__ unsigned int ls[256];
    const int t = threadIdx.x;
    const long base = (long)blockIdx.x * 1024 + (long)t * 4;
    unsigned int v0 = (base     < n) ? in[base]     : 0u;
    unsigned int v1 = (base + 1 < n) ? in[base + 1] : 0u;
    unsigned int v2 = (base + 2 < n) ? in[base + 2] : 0u;
    unsigned int v3 = (base + 3 < n) ? in[base + 3] : 0u;
    const unsigned int s = v0 + v1 + v2 + v3;
    ls[t] = s;
    __syncthreads();
    for (int off = 1; off < 256; off <<= 1) {
        unsigned int x = (t >= off) ? ls[t - off] : 0u;
        __syncthreads();
        ls[t] += x;
        __syncthreads();
    }
    const unsigned int ex = ls[t] - s;
    if (base     < n) out[base]     = ex;
    if (base + 1 < n) out[base + 1] = ex + v0;
    if (base + 2 < n) out[base + 2] = ex + v0 + v1;
    if (base + 3 < n) out[base + 3] = ex + v0 + v1 + v2;
    if (aux != nullptr && t == 255) aux[blockIdx.x] = ls[255];
}

__global__ void addback_kernel(unsigned int* __restrict__ out, const unsigned int* __restrict__ aux, int n) {
    const long i = (long)blockIdx.x * 256 + threadIdx.x;
    if (i < n) out[i] += aux[i >> 10];
}

// FIX vs round 3: store the GATHER ROW (cv_in[k][i]) in entries, not the position i.
__global__ void scatter_kernel(const int* __restrict__ cv_in,
                               const int* __restrict__ cv_out,
                               const unsigned int* __restrict__ start,
                               unsigned int* __restrict__ hist,       // counts, consumed
                               unsigned int* __restrict__ entries) {
    const int i = blockIdx.x * 256 + threadIdx.x;
    const int k = blockIdx.y;
    const long p = (long)k * NUP + i;
    const int j = cv_out[p];
    const long bin = (long)k * NUP + j;
    const unsigned int off = atomicSub(&hist[bin], 1u) - 1u;
    entries[start[bin] + off] = (unsigned int)cv_in[p];
}

// ---------------- conv in GATHER form: zero atomics, fused ReLU, direct stores ----------------
__global__ __launch_bounds__(256, 2)
void conv_inv(const unsigned short* __restrict__ cat,
              const unsigned short* __restrict__ WcT,
              const unsigned int* __restrict__ start,
              const unsigned int* __restrict__ entries,
              float* __restrict__ out) {
    __shared__ __align__(1024) unsigned short sA[TM * CCAT];    // 24.6 KB
    __shared__ __align__(1024) unsigned short sB[COUT * CCAT];  // 36.9 KB

    const int j0 = blockIdx.x * TM;
    const int t = threadIdx.x;
    const int wave = t >> 6, lane = t & 63;
    const int col = lane & 15, quad = lane >> 4;
    const int wm = wave & 1, wn = wave >> 1;
    const int r  = t >> 2;           // staging row 0..63 (4 threads/row)
    const int cq = (t & 3) * 6;      // staging chunk base (6 chunks of 16B = 48 elems)

    f32x4 acc[2][3];
#pragma unroll
    for (int mi = 0; mi < 2; mi++)
#pragma unroll
        for (int nt = 0; nt < 3; nt++) acc[mi][nt] = (f32x4){0.f, 0.f, 0.f, 0.f};

    char* sAc = (char*)sA;
    char* sBc = (char*)sB;

    for (int k = 0; k < K_OFF; k++) {
        const long kb = (long)k * NUP;
        const unsigned int s0 = start[kb + j0 + r];
        const long i1 = kb + j0 + r + 1;
        const unsigned int s1 = (i1 == (long)B_BINS) ? (unsigned int)B_BINS : start[i1];
        const int n = (int)(s1 - s0);

        uint4 ch[6];
        if (n == 1) {                                  // common path: pure bf16 row copy
            const unsigned int ie = entries[s0];       // = cv_in row
            const uint4* src = (const uint4*)(cat + (long)ie * CCAT) + cq;
#pragma unroll
            for (int q = 0; q < 6; q++) ch[q] = src[q];
        } else if (n == 0) {
#pragma unroll
            for (int q = 0; q < 6; q++) ch[q] = make_uint4(0u, 0u, 0u, 0u);
        } else {                                       // duplicates: f32 sum, one bf16 round
            float fa[6][8];
#pragma unroll
            for (int q = 0; q < 6; q++)
#pragma unroll
                for (int e8 = 0; e8 < 8; e8++) fa[q][e8] = 0.f;
            for (unsigned int e = s0; e < s1; e++) {
                const unsigned int ie = entries[e];
                const uint4* src = (const uint4*)(cat + (long)ie * CCAT) + cq;
#pragma unroll
                for (int q = 0; q < 6; q++) {
                    uint4 c = src[q];
                    fa[q][0] += b2f(c.x & 0xffffu); fa[q][1] += b2f(c.x >> 16);
                    fa[q][2] += b2f(c.y & 0xffffu); fa[q][3] += b2f(c.y >> 16);
                    fa[q][4] += b2f(c.z & 0xffffu); fa[q][5] += b2f(c.z >> 16);
                    fa[q][6] += b2f(c.w & 0xffffu); fa[q][7] += b2f(c.w >> 16);
                }
            }
#pragma unroll
            for (int q = 0; q < 6; q++) {
                ch[q].x = pk2(fa[q][0], fa[q][1]);
                ch[q].y = pk2(fa[q][2], fa[q][3]);
                ch[q].z = pk2(fa[q][4], fa[q][5]);
                ch[q].w = pk2(fa[q][6], fa[q][7]);
            }
        }

        // B tile chunks -> regs (2304 chunks, 9/thread)
        uint4 bc[9];
        const uint4* wsrc = (const uint4*)(WcT + (long)k * COUT * CCAT);
#pragma unroll
        for (int p = 0; p < 9; p++) bc[p] = wsrc[t + 256 * p];

        __syncthreads();   // previous k's ds_reads complete

        // A writes, swizzled
#pragma unroll
        for (int q = 0; q < 6; q++) {
            const int cc = cq + q;
            *(uint4*)(sAc + r * 384 + ((cc ^ (r & 7)) << 4)) = ch[q];
        }
        // B writes, same swizzle on [96][192]
#pragma unroll
        for (int p = 0; p < 9; p++) {
            const int c = t + 256 * p;
            const int nn = c / 24, cc = c % 24;
            *(uint4*)(sBc + nn * 384 + ((cc ^ (nn & 7)) << 4)) = bc[p];
        }
        __syncthreads();

#pragma unroll
        for (int kk = 0; kk < 6; kk++) {
            const int c2 = kk * 4 + quad;
            const int row0 = wm * 32 + col;
            const int row1 = row0 + 16;
            bf16x8 a0 = *(const bf16x8*)(sAc + row0 * 384 + ((c2 ^ (row0 & 7)) << 4));
            bf16x8 a1 = *(const bf16x8*)(sAc + row1 * 384 + ((c2 ^ (row1 & 7)) << 4));
#pragma unroll
            for (int nt = 0; nt < 3; nt++) {
                const int bn = wn * 48 + nt * 16 + col;
                bf16x8 bb = *(const bf16x8*)(sBc + bn * 384 + ((c2 ^ (bn & 7)) << 4));
                acc[0][nt] = __builtin_amdgcn_mfma_f32_16x16x32_bf16(a0, bb, acc[0][nt], 0, 0, 0);
                acc[1][nt] = __builtin_amdgcn_mfma_f32_16x16x32_bf16(a1, bb, acc[1][nt], 0, 0, 0);
            }
        }
    }

    // epilogue: fused ReLU + plain coalesced stores (full coverage, no memset needed)
#pragma unroll
    for (int mi = 0; mi < 2; mi++)
#pragma unroll
        for (int rr = 0; rr < 4; rr++) {
            const int lrow = wm * 32 + mi * 16 + quad * 4 + rr;
            float* op = out + (long)(j0 + lrow) * COUT + wn * 48 + col;
#pragma unroll
            for (int nt = 0; nt < 3; nt++)
                op[nt * 16] = fmaxf(acc[mi][nt][rr], 0.f);
        }
}

// ================= fallback path (ws too small) =================
#define SA1 136
#define SB1 136

__global__ __launch_bounds__(256, 2)
void deconv_kernel(const float* __restrict__ down,
                   const float* __restrict__ Wd,
                   const int* __restrict__ in_idx,
                   const int* __restrict__ out_idx,
                   float* __restrict__ up) {
    __shared__ __align__(16) unsigned short sA[TM * SA1];
    __shared__ __align__(16) unsigned short sB[CDOWN * SB1];
    __shared__ int sOut[TM];

    const int tiles = NDOWN / TM;
    const int bk = blockIdx.x / tiles;
    const int tile = blockIdx.x % tiles;
    const int t = threadIdx.x;
    const long kInBase = (long)bk * NDOWN + tile * TM;

    {
        const int r = t >> 2;
        const int c0 = (t & 3) * 32;
        const int j = in_idx[kInBase + r];
        const float* src = down + (long)j * CDOWN + c0;
        unsigned short* dst = sA + r * SA1 + c0;
        #pragma unroll
        for (int c = 0; c < 32; c += 4) {
            float4 v = *(const float4*)(src + c);
            *(unsigned int*)(dst + c)     = pk2(v.x, v.y);
            *(unsigned int*)(dst + c + 2) = pk2(v.z, v.w);
        }
    }
    {
        const float* wsrc = Wd + (long)bk * CDOWN * CDOWN;
        for (int idx = t; idx < CDOWN * CDOWN; idx += 256) {
            const int kk = idx >> 7;
            const int n  = idx & 127;
            sB[n * SB1 + kk] = f2b(wsrc[idx]);
        }
    }
    if (t < TM) sOut[t] = out_idx[kInBase + t];
    __syncthreads();

    const int wave = t >> 6;
    const int lane = t & 63;
    const int col  = lane & 15;
    const int quad = lane >> 4;
    const int mrow = wave * 16 + col;

    f32x4 acc[8];
    #pragma unroll
    for (int i = 0; i < 8; i++) acc[i] = (f32x4){0.f, 0.f, 0.f, 0.f};

    #pragma unroll
    for (int k0 = 0; k0 < CDOWN; k0 += 32) {
        const int koff = k0 + quad * 8;
        bf16x8 a = *(const bf16x8*)&sA[mrow * SA1 + koff];
        #pragma unroll
        for (int nt = 0; nt < 8; nt++) {
            bf16x8 bb = *(const bf16x8*)&sB[(nt * 16 + col) * SB1 + koff];
            acc[nt] = __builtin_amdgcn_mfma_f32_16x16x32_bf16(a, bb, acc[nt], 0, 0, 0);
        }
    }
    #pragma unroll
    for (int r = 0; r < 4; r++) {
        const int lrow = wave * 16 + quad * 4 + r;
        const long obase = (long)sOut[lrow] * CDOWN;
        #pragma unroll
        for (int nt = 0; nt < 8; nt++)
            atomicAdd(&up[obase + nt * 16 + col], acc[nt][r]);
    }
}

#define SA2 200
#define SB2 200

__global__ __launch_bounds__(256, 2)
void conv_kernel(const float* __restrict__ up,
                 const float* __restrict__ skip,
                 const float* __restrict__ Wc,
                 const int* __restrict__ in_idx,
                 const int* __restrict__ out_idx,
                 float* __restrict__ out) {
    __shared__ __align__(16) unsigned short sA[TM * SA2];
    __shared__ __align__(16) unsigned short sB[COUT * SB2];
    __shared__ int sOut[TM];

    const int tiles = NUP / TM;
    const int bk = blockIdx.x / tiles;
    const int tile = blockIdx.x % tiles;
    const int t = threadIdx.x;
    const long kInBase = (long)bk * NUP + tile * TM;

    {
        const int r = t >> 2;
        const int c0 = (t & 3) * 48;
        const int j = in_idx[kInBase + r];
        const float* uprow = up + (long)j * CDOWN;
        const float* skrow = skip + (long)j * CSKIP;
        unsigned short* dst = sA + r * SA2 + c0;
        #pragma unroll
        for (int c = 0; c < 48; c += 4) {
            const int gc = c0 + c;
            float4 v;
            if (gc < CDOWN) {
                v = *(const float4*)(uprow + gc);
                v.x = fmaxf(v.x, 0.f); v.y = fmaxf(v.y, 0.f);
                v.z = fmaxf(v.z, 0.f); v.w = fmaxf(v.w, 0.f);
            } else {
                v = *(const float4*)(skrow + (gc - CDOWN));
            }
            *(unsigned int*)(dst + c)     = pk2(v.x, v.y);
            *(unsigned int*)(dst + c + 2) = pk2(v.z, v.w);
        }
    }
    {
        const float* wsrc = Wc + (long)bk * CCAT * COUT;
        for (int idx = t; idx < CCAT * COUT; idx += 256) {
            const int kk = idx / COUT;
            const int n  = idx - kk * COUT;
            sB[n * SB2 + kk] = f2b(wsrc[idx]);
        }
    }
    if (t < TM) sOut[t] = out_idx[kInBase + t];
    __syncthreads();

    const int wave = t >> 6;
    const int lane = t & 63;
    const int col  = lane & 15;
    const int quad = lane >> 4;
    const int mrow = wave * 16 + col;

    f32x4 acc[6];
    #pragma unroll
    for (int i = 0; i < 6; i++) acc[i] = (f32x4){0.f, 0.f, 0.f, 0.f};

    #pragma unroll
    for (int k0 = 0; k0 < CCAT; k0 += 32) {
        const int koff = k0 + quad * 8;
        bf16x8 a = *(const bf16x8*)&sA[mrow * SA2 + koff];
        #pragma unroll
        for (int nt = 0; nt < 6; nt++) {
            bf16x8 bb = *(const bf16x8*)&sB[(nt * 16 + col) * SB2 + koff];
            acc[nt] = __builtin_amdgcn_mfma_f32_16x16x32_bf16(a, bb, acc[nt], 0, 0, 0);
        }
    }
    #pragma unroll
    for (int r = 0; r < 4; r++) {
        const int lrow = wave * 16 + quad * 4 + r;
        const long obase = (long)sOut[lrow] * COUT;
        #pragma unroll
        for (int nt = 0; nt < 6; nt++)
            atomicAdd(&out[obase + nt * 16 + col], acc[nt][r]);
    }
}

__global__ void relu_kernel(float* __restrict__ x, int n4) {
    int i = blockIdx.x * blockDim.x + threadIdx.x;
    if (i < n4) {
        float4 v = ((float4*)x)[i];
        v.x = fmaxf(v.x, 0.f); v.y = fmaxf(v.y, 0.f);
        v.z = fmaxf(v.z, 0.f); v.w = fmaxf(v.w, 0.f);
        ((float4*)x)[i] = v;
    }
}

extern "C" void kernel_launch(void* const* d_in, const int* in_sizes, int n_in,
                              void* d_out, int out_size, void* d_ws, size_t ws_size,
                              hipStream_t stream) {
    const float* skip   = (const float*)d_in[0];
    const float* down   = (const float*)d_in[1];
    const float* Wd     = (const float*)d_in[2];
    const float* Wc     = (const float*)d_in[3];
    const int* dc_in    = (const int*)d_in[4];
    const int* dc_out   = (const int*)d_in[5];
    const int* cv_in    = (const int*)d_in[6];
    const int* cv_out   = (const int*)d_in[7];
    float* out = (float*)d_out;
    float* up  = (float*)d_ws;                   // [NUP][CDOWN] f32, dead after pack_cat

    const size_t OFF_CAT = (size_t)NUP * CDOWN * 4;                    //  81,920,000
    const size_t OFF_DBF = OFF_CAT + (size_t)NUP * CCAT * 2;           // 143,360,000
    const size_t OFF_WDT = OFF_DBF + (size_t)NDOWN * CDOWN * 2;        // 153,600,000
    const size_t OFF_WCT = OFF_WDT + (size_t)K_OFF * CDOWN * CDOWN * 2;// 154,484,736
    const size_t WS_NEED = OFF_WCT + (size_t)K_OFF * COUT * CCAT * 2;  // 155,480,064

    hipMemsetAsync(up, 0, (size_t)NUP * CDOWN * sizeof(float), stream);

    if (ws_size >= WS_NEED) {
        unsigned short* catb = (unsigned short*)((char*)d_ws + OFF_CAT);
        unsigned short* dbf  = (unsigned short*)((char*)d_ws + OFF_DBF);
        unsigned short* WdT  = (unsigned short*)((char*)d_ws + OFF_WDT);
        unsigned short* WcT  = (unsigned short*)((char*)d_ws + OFF_WCT);

        // CSR scratch overlays the `up` region (only touched AFTER pack_cat);
        // histogram overlays d_out (conv_inv rewrites every element afterwards).
        unsigned int* entriesC = (unsigned int*)d_ws;                           // 17.28 MB
        unsigned int* startC   = (unsigned int*)((char*)d_ws + 17280000);       // 17.28 MB
        unsigned int* aux1     = (unsigned int*)((char*)d_ws + 34560000);       // 4219*4 B
        unsigned int* aux2     = (unsigned int*)((char*)d_ws + 34580000);       // 5*4 B
        unsigned int* hist     = (unsigned int*)d_out;                          // 17.28 MB

        pack_down_kernel<<<(NDOWN * CDOWN / 8 + 255) / 256, 256, 0, stream>>>(down, dbf);
        pack_w_kernel<<<(K_OFF * COUT * CCAT + 255) / 256, 256, 0, stream>>>(Wd, Wc, WdT, WcT);
        deconv_fast<<<K_OFF * ((NDOWN / TM) / MT_D), 256, 0, stream>>>(dbf, WdT, dc_in, dc_out, up);
        pack_cat_kernel<<<NUP / 8, 192, 0, stream>>>(up, skip, catb);
        // ---- up region now dead; build inverse CSR for conv ----
        hipMemsetAsync(hist, 0, (size_t)B_BINS * 4, stream);
        hist_kernel<<<dim3(NUP / 256, K_OFF), 256, 0, stream>>>(cv_out, hist);
        const int nblk1 = (B_BINS + 1023) / 1024;                // 4219
        const int nblk2 = (nblk1 + 1023) / 1024;                 // 5
        scan_blocks<<<nblk1, 256, 0, stream>>>(hist, startC, aux1, B_BINS);
        scan_blocks<<<nblk2, 256, 0, stream>>>(aux1, aux1, aux2, nblk1);
        scan_blocks<<<1, 256, 0, stream>>>(aux2, aux2, nullptr, nblk2);
        addback_kernel<<<(nblk1 + 255) / 256, 256, 0, stream>>>(aux1, aux2, nblk1);
        addback_kernel<<<(B_BINS + 255) / 256, 256, 0, stream>>>(startC, aux1, B_BINS);
        scatter_kernel<<<dim3(NUP / 256, K_OFF), 256, 0, stream>>>(cv_in, cv_out, startC, hist, entriesC);
        // ---- gather-form conv: no atomics, fused ReLU, full-coverage stores ----
        conv_inv<<<NUP / TM, 256, 0, stream>>>(catb, WcT, startC, entriesC, out);
    } else {
        hipMemsetAsync(out, 0, (size_t)out_size * sizeof(float), stream);
        deconv_kernel<<<K_OFF * (NDOWN / TM), 256, 0, stream>>>(down, Wd, dc_in, dc_out, up);
        conv_kernel<<<K_OFF * (NUP / TM), 256, 0, stream>>>(up, skip, Wc, cv_in, cv_out, out);
        relu_kernel<<<(out_size / 4 + 255) / 256, 256, 0, stream>>>(out, out_size / 4);
    }
}